// Round 1
// 4996.722 us; speedup vs baseline: 1.9783x; 1.9783x over previous
//
#include <hip/hip_runtime.h>
#include <math.h>

// ---------------- problem constants ----------------
#define TB    2048      // T
#define CDIM  1024      // C
#define NTOKS 4096      // B*T
#define NH    16
#define NKV   4
#define DHD   64
#define FFD   4096
#define NEXP  8
#define WINSZ 1024
#define QKVD  1536      // packed q(1024)+k(256)+v(256) row stride
#define KOFS  1024
#define VOFS  1280

// ---------------- wave helpers ----------------
__device__ __forceinline__ float waveSum(float v) {
#pragma unroll
  for (int o = 32; o; o >>= 1) v += __shfl_xor(v, o, 64);
  return v;
}

// ---------------- RMSNorm: one block per token row ----------------
__global__ __launch_bounds__(256) void rmsnorm_kernel(
    const float* __restrict__ x, const float* __restrict__ w, float* __restrict__ o) {
  int n = blockIdx.x;
  const float* xr = x + (size_t)n * CDIM;
  float s = 0.f;
  for (int i = threadIdx.x; i < CDIM; i += 256) { float v = xr[i]; s += v * v; }
  s = waveSum(s);
  __shared__ float sm[4];
  if ((threadIdx.x & 63) == 0) sm[threadIdx.x >> 6] = s;
  __syncthreads();
  float tot = sm[0] + sm[1] + sm[2] + sm[3];
  float r = rsqrtf(tot * (1.f / CDIM) + 1e-6f);
  float* orow = o + (size_t)n * CDIM;
  for (int i = threadIdx.x; i < CDIM; i += 256) orow[i] = xr[i] * r * w[i];
}

// ---------------- pack wq|wk|wv into [C][1536] ----------------
__global__ __launch_bounds__(256) void packqkv_kernel(
    const float* __restrict__ wq, const float* __restrict__ wk,
    const float* __restrict__ wv, float* __restrict__ wp) {
  int c = blockIdx.x;  // 0..1023
  for (int j = threadIdx.x; j < QKVD; j += 256) {
    float v;
    if (j < 1024)      v = wq[(size_t)c * 1024 + j];
    else if (j < 1280) v = wk[(size_t)c * 256 + (j - 1024)];
    else               v = wv[(size_t)c * 256 + (j - 1280)];
    wp[(size_t)c * QKVD + j] = v;
  }
}

// ---------------- generic tiled f32 GEMM ----------------
// gridDim.z = expert index (weights at B + z*bStride, rows from ofsPtr/cntPtr[z]).
#define BM 128
#define BN 128
#define BK 16

template <int OP>
__global__ __launch_bounds__(256) void gemm_kernel(
    const float* __restrict__ A, const float* __restrict__ Bmat, float* __restrict__ C,
    int M, int Nn, int Kd,
    const int* __restrict__ rowIdx, const int* __restrict__ ofsPtr,
    const int* __restrict__ cntPtr, size_t bStride,
    const float* __restrict__ Dres, const float* __restrict__ alphaPtr,
    const float* __restrict__ rowScale) {
  int e = blockIdx.z;
  int ofs = ofsPtr ? ofsPtr[e] : 0;
  int Mloc = cntPtr ? cntPtr[e] : M;
  int rowTile = blockIdx.y * BM;
  if (rowTile >= Mloc) return;
  int colTile = blockIdx.x * BN;
  const float* B = Bmat + (size_t)e * bStride;

  __shared__ float As[BK][BM + 4];  // transposed: As[k][m]
  __shared__ float Bs[BK][BN + 4];

  int tid = threadIdx.x;
  int tx = tid & 15, ty = tid >> 4;

  int s0 = tid, s1 = tid + 256;
  int ar0 = s0 >> 2, ac0 = (s0 & 3) * 4;
  int ar1 = s1 >> 2, ac1 = (s1 & 3) * 4;
  int g0 = rowTile + ar0, g1 = rowTile + ar1;
  const float* ap0 = nullptr;
  const float* ap1 = nullptr;
  if (g0 < Mloc) { int r = rowIdx ? rowIdx[ofs + g0] : (ofs + g0); ap0 = A + (size_t)r * Kd + ac0; }
  if (g1 < Mloc) { int r = rowIdx ? rowIdx[ofs + g1] : (ofs + g1); ap1 = A + (size_t)r * Kd + ac1; }
  int br0 = s0 >> 5, bc0 = (s0 & 31) * 4;
  int br1 = s1 >> 5, bc1 = (s1 & 31) * 4;
  const float* bp0 = B + (size_t)br0 * Nn + colTile + bc0;
  const float* bp1 = B + (size_t)br1 * Nn + colTile + bc1;

  float acc[8][8];
#pragma unroll
  for (int i = 0; i < 8; i++)
#pragma unroll
    for (int j = 0; j < 8; j++) acc[i][j] = 0.f;

  for (int kt = 0; kt < Kd; kt += BK) {
    float4 a0 = ap0 ? *(const float4*)(ap0 + kt) : make_float4(0.f, 0.f, 0.f, 0.f);
    float4 a1 = ap1 ? *(const float4*)(ap1 + kt) : make_float4(0.f, 0.f, 0.f, 0.f);
    float4 b0 = *(const float4*)(bp0 + (size_t)kt * Nn);
    float4 b1 = *(const float4*)(bp1 + (size_t)kt * Nn);
    __syncthreads();
    As[ac0 + 0][ar0] = a0.x; As[ac0 + 1][ar0] = a0.y; As[ac0 + 2][ar0] = a0.z; As[ac0 + 3][ar0] = a0.w;
    As[ac1 + 0][ar1] = a1.x; As[ac1 + 1][ar1] = a1.y; As[ac1 + 2][ar1] = a1.z; As[ac1 + 3][ar1] = a1.w;
    *(float4*)&Bs[br0][bc0] = b0;
    *(float4*)&Bs[br1][bc1] = b1;
    __syncthreads();
#pragma unroll
    for (int kk = 0; kk < BK; kk++) {
      float a[8], b[8];
      float4 t0 = *(const float4*)&As[kk][ty * 4];
      float4 t1 = *(const float4*)&As[kk][64 + ty * 4];
      float4 t2 = *(const float4*)&Bs[kk][tx * 4];
      float4 t3 = *(const float4*)&Bs[kk][64 + tx * 4];
      a[0] = t0.x; a[1] = t0.y; a[2] = t0.z; a[3] = t0.w;
      a[4] = t1.x; a[5] = t1.y; a[6] = t1.z; a[7] = t1.w;
      b[0] = t2.x; b[1] = t2.y; b[2] = t2.z; b[3] = t2.w;
      b[4] = t3.x; b[5] = t3.y; b[6] = t3.z; b[7] = t3.w;
#pragma unroll
      for (int i = 0; i < 8; i++)
#pragma unroll
        for (int j = 0; j < 8; j++) acc[i][j] = fmaf(a[i], b[j], acc[i][j]);
    }
  }

#pragma unroll
  for (int ii = 0; ii < 8; ii++) {
    int r = (ii < 4) ? (ty * 4 + ii) : (64 + ty * 4 + (ii - 4));
    int gr = rowTile + r;
    if (gr >= Mloc) continue;
    size_t crow = (size_t)(ofs + gr) * Nn;
#pragma unroll
    for (int jj = 0; jj < 2; jj++) {
      int c = colTile + (jj ? (64 + tx * 4) : (tx * 4));
      float* cp = C + crow + c;
      float4 vv = make_float4(acc[ii][jj * 4 + 0], acc[ii][jj * 4 + 1],
                              acc[ii][jj * 4 + 2], acc[ii][jj * 4 + 3]);
      if (OP == 0) {
        *(float4*)cp = vv;
      } else if (OP == 2) {
        float al = alphaPtr[0];
        float4 dd = *(const float4*)(Dres + crow + c);
        float4 ov = make_float4(dd.x + al * vv.x, dd.y + al * vv.y,
                                dd.z + al * vv.z, dd.w + al * vv.w);
        *(float4*)cp = ov;
      } else {
        float rs = rowScale[ofs + gr];
        float4 ov = make_float4(vv.x * rs, vv.y * rs, vv.z * rs, vv.w * rs);
        *(float4*)cp = ov;
      }
    }
  }
}

// ---------------- fused SwiGLU up-projection: C = silu(A@W1) * (A@W2) ----------------
// 128x64 output tile per block; gridDim.z = expert (weights at W + z*wStride).
#define UBN 64

__global__ __launch_bounds__(256) void gemm_up_kernel(
    const float* __restrict__ A, const float* __restrict__ W1,
    const float* __restrict__ W2, float* __restrict__ Cout, int M,
    const int* __restrict__ rowIdx, const int* __restrict__ ofsPtr,
    const int* __restrict__ cntPtr, size_t wStride) {
  int e = blockIdx.z;
  int ofs = ofsPtr ? ofsPtr[e] : 0;
  int Mloc = cntPtr ? cntPtr[e] : M;
  int rowTile = blockIdx.y * BM;
  if (rowTile >= Mloc) return;
  int colTile = blockIdx.x * UBN;
  const float* B1 = W1 + (size_t)e * wStride;
  const float* B2 = W2 + (size_t)e * wStride;

  __shared__ float As[BK][BM + 4];
  __shared__ float B1s[BK][UBN + 4];
  __shared__ float B2s[BK][UBN + 4];

  int tid = threadIdx.x;
  int tx = tid & 15, ty = tid >> 4;

  int s0 = tid, s1 = tid + 256;
  int ar0 = s0 >> 2, ac0 = (s0 & 3) * 4;
  int ar1 = s1 >> 2, ac1 = (s1 & 3) * 4;
  int g0 = rowTile + ar0, g1 = rowTile + ar1;
  const float* ap0 = nullptr;
  const float* ap1 = nullptr;
  if (g0 < Mloc) { int r = rowIdx ? rowIdx[ofs + g0] : (ofs + g0); ap0 = A + (size_t)r * CDIM + ac0; }
  if (g1 < Mloc) { int r = rowIdx ? rowIdx[ofs + g1] : (ofs + g1); ap1 = A + (size_t)r * CDIM + ac1; }
  int br = tid >> 4;        // k row 0..15
  int bc = (tid & 15) * 4;  // col 0..60
  const float* b1p = B1 + (size_t)br * FFD + colTile + bc;
  const float* b2p = B2 + (size_t)br * FFD + colTile + bc;

  float acc1[8][4], acc2[8][4];
#pragma unroll
  for (int i = 0; i < 8; i++)
#pragma unroll
    for (int j = 0; j < 4; j++) { acc1[i][j] = 0.f; acc2[i][j] = 0.f; }

  for (int kt = 0; kt < CDIM; kt += BK) {
    float4 a0 = ap0 ? *(const float4*)(ap0 + kt) : make_float4(0.f, 0.f, 0.f, 0.f);
    float4 a1 = ap1 ? *(const float4*)(ap1 + kt) : make_float4(0.f, 0.f, 0.f, 0.f);
    float4 w1 = *(const float4*)(b1p + (size_t)kt * FFD);
    float4 w2 = *(const float4*)(b2p + (size_t)kt * FFD);
    __syncthreads();
    As[ac0 + 0][ar0] = a0.x; As[ac0 + 1][ar0] = a0.y; As[ac0 + 2][ar0] = a0.z; As[ac0 + 3][ar0] = a0.w;
    As[ac1 + 0][ar1] = a1.x; As[ac1 + 1][ar1] = a1.y; As[ac1 + 2][ar1] = a1.z; As[ac1 + 3][ar1] = a1.w;
    *(float4*)&B1s[br][bc] = w1;
    *(float4*)&B2s[br][bc] = w2;
    __syncthreads();
#pragma unroll
    for (int kk = 0; kk < BK; kk++) {
      float a[8];
      float4 t0 = *(const float4*)&As[kk][ty * 4];
      float4 t1 = *(const float4*)&As[kk][64 + ty * 4];
      float4 u = *(const float4*)&B1s[kk][tx * 4];
      float4 g = *(const float4*)&B2s[kk][tx * 4];
      a[0] = t0.x; a[1] = t0.y; a[2] = t0.z; a[3] = t0.w;
      a[4] = t1.x; a[5] = t1.y; a[6] = t1.z; a[7] = t1.w;
#pragma unroll
      for (int i = 0; i < 8; i++) {
        acc1[i][0] = fmaf(a[i], u.x, acc1[i][0]);
        acc1[i][1] = fmaf(a[i], u.y, acc1[i][1]);
        acc1[i][2] = fmaf(a[i], u.z, acc1[i][2]);
        acc1[i][3] = fmaf(a[i], u.w, acc1[i][3]);
        acc2[i][0] = fmaf(a[i], g.x, acc2[i][0]);
        acc2[i][1] = fmaf(a[i], g.y, acc2[i][1]);
        acc2[i][2] = fmaf(a[i], g.z, acc2[i][2]);
        acc2[i][3] = fmaf(a[i], g.w, acc2[i][3]);
      }
    }
  }

#pragma unroll
  for (int ii = 0; ii < 8; ii++) {
    int r = (ii < 4) ? (ty * 4 + ii) : (64 + ty * 4 + (ii - 4));
    int gr = rowTile + r;
    if (gr >= Mloc) continue;
    float* cp = Cout + (size_t)(ofs + gr) * FFD + colTile + tx * 4;
    float4 ov;
    ov.x = (acc1[ii][0] / (1.f + __expf(-acc1[ii][0]))) * acc2[ii][0];
    ov.y = (acc1[ii][1] / (1.f + __expf(-acc1[ii][1]))) * acc2[ii][1];
    ov.z = (acc1[ii][2] / (1.f + __expf(-acc1[ii][2]))) * acc2[ii][2];
    ov.w = (acc1[ii][3] / (1.f + __expf(-acc1[ii][3]))) * acc2[ii][3];
    *(float4*)cp = ov;
  }
}

// ---------------- RoPE (in-place on packed qkv buffer) ----------------
__device__ __forceinline__ void rope_one(float* row, int t, int j) {
  float invf = __expf(-(float)j * (9.210340371976184f / 32.f));  // ln(10000)/32
  float ang = (float)t * invf;
  float c = cosf(ang), s = sinf(ang);
  float u0 = row[j], u1 = row[j + 32];
  row[j] = u0 * c - u1 * s;
  row[j + 32] = u1 * c + u0 * s;
}

__global__ __launch_bounds__(256) void rope_kernel(float* __restrict__ qkv) {
  int gid = blockIdx.x * 256 + threadIdx.x;
  const int QN = NTOKS * NH * 32;
  const int KN = NTOKS * NKV * 32;
  if (gid < QN) {
    int j = gid & 31;
    int h = (gid >> 5) & (NH - 1);
    int n = gid >> 9;
    rope_one(qkv + (size_t)n * QKVD + h * DHD, n & (TB - 1), j);
  } else if (gid < QN + KN) {
    int g2 = gid - QN;
    int j = g2 & 31;
    int g = (g2 >> 5) & (NKV - 1);
    int n = g2 >> 7;
    rope_one(qkv + (size_t)n * QKVD + KOFS + g * DHD, n & (TB - 1), j);
  }
}

// ---------------- flash attention: one block per (b, h, 64-query tile) ----------------
#define LSTR 68

__global__ __launch_bounds__(256) void attn_kernel(
    const float* __restrict__ qkv, float* __restrict__ o) {
  __shared__ float Qs[64 * LSTR];
  __shared__ float KP[64 * LSTR];
  __shared__ float Vs[64 * LSTR];

  int tid = threadIdx.x;
  int tx = tid & 15, ty = tid >> 4;
  int qt = blockIdx.x & 31;
  int h = (blockIdx.x >> 5) & (NH - 1);
  int b = blockIdx.x >> 9;
  int g = h >> 2;  // kv group (NREP=4)
  int q0 = qt * 64;

#pragma unroll
  for (int i = 0; i < 4; i++) {
    int slot = tid + 256 * i;
    int r = slot >> 4, c = (slot & 15) * 4;
    float4 qv = *(const float4*)&qkv[(size_t)(b * TB + q0 + r) * QKVD + h * DHD + c];
    *(float4*)&Qs[r * LSTR + c] = qv;
  }

  float O[4][4], S[4][4], m[4], l[4];
#pragma unroll
  for (int i = 0; i < 4; i++) {
    m[i] = -1e30f; l[i] = 0.f;
#pragma unroll
    for (int j = 0; j < 4; j++) O[i][j] = 0.f;
  }

  int kt0 = q0 - WINSZ; if (kt0 < 0) kt0 = 0;
  for (int kt = kt0; kt <= q0; kt += 64) {
    __syncthreads();  // prev PV done
#pragma unroll
    for (int i = 0; i < 4; i++) {
      int slot = tid + 256 * i;
      int r = slot >> 4, c = (slot & 15) * 4;
      const float* krow = &qkv[(size_t)(b * TB + kt + r) * QKVD + KOFS + g * DHD + c];
      float4 kv = *(const float4*)krow;
      KP[(c + 0) * LSTR + r] = kv.x;
      KP[(c + 1) * LSTR + r] = kv.y;
      KP[(c + 2) * LSTR + r] = kv.z;
      KP[(c + 3) * LSTR + r] = kv.w;
      const float* vrow = &qkv[(size_t)(b * TB + kt + r) * QKVD + VOFS + g * DHD + c];
      *(float4*)&Vs[r * LSTR + c] = *(const float4*)vrow;
    }
    __syncthreads();

#pragma unroll
    for (int i = 0; i < 4; i++)
#pragma unroll
      for (int j = 0; j < 4; j++) S[i][j] = 0.f;
#pragma unroll 4
    for (int d = 0; d < 64; d++) {
      float4 k4 = *(const float4*)&KP[d * LSTR + tx * 4];
      float q0v = Qs[(ty * 4 + 0) * LSTR + d];
      float q1v = Qs[(ty * 4 + 1) * LSTR + d];
      float q2v = Qs[(ty * 4 + 2) * LSTR + d];
      float q3v = Qs[(ty * 4 + 3) * LSTR + d];
      S[0][0] = fmaf(q0v, k4.x, S[0][0]); S[0][1] = fmaf(q0v, k4.y, S[0][1]);
      S[0][2] = fmaf(q0v, k4.z, S[0][2]); S[0][3] = fmaf(q0v, k4.w, S[0][3]);
      S[1][0] = fmaf(q1v, k4.x, S[1][0]); S[1][1] = fmaf(q1v, k4.y, S[1][1]);
      S[1][2] = fmaf(q1v, k4.z, S[1][2]); S[1][3] = fmaf(q1v, k4.w, S[1][3]);
      S[2][0] = fmaf(q2v, k4.x, S[2][0]); S[2][1] = fmaf(q2v, k4.y, S[2][1]);
      S[2][2] = fmaf(q2v, k4.z, S[2][2]); S[2][3] = fmaf(q2v, k4.w, S[2][3]);
      S[3][0] = fmaf(q3v, k4.x, S[3][0]); S[3][1] = fmaf(q3v, k4.y, S[3][1]);
      S[3][2] = fmaf(q3v, k4.z, S[3][2]); S[3][3] = fmaf(q3v, k4.w, S[3][3]);
    }

    int maskDiag = (kt == q0);
    int maskEdge = (kt == q0 - WINSZ);
#pragma unroll
    for (int qi = 0; qi < 4; qi++) {
      int qg = q0 + ty * 4 + qi;
#pragma unroll
      for (int ji = 0; ji < 4; ji++) {
        int kj = kt + tx * 4 + ji;
        float s = S[qi][ji] * 0.125f;  // 1/sqrt(64)
        if (maskDiag && kj > qg) s = -1e30f;
        if (maskEdge && kj < qg - WINSZ) s = -1e30f;
        S[qi][ji] = s;
      }
      float mloc = fmaxf(fmaxf(S[qi][0], S[qi][1]), fmaxf(S[qi][2], S[qi][3]));
#pragma unroll
      for (int off = 1; off < 16; off <<= 1) mloc = fmaxf(mloc, __shfl_xor(mloc, off, 64));
      float mnew = fmaxf(m[qi], mloc);
      float sc = __expf(m[qi] - mnew);
      float psum = 0.f;
#pragma unroll
      for (int ji = 0; ji < 4; ji++) {
        float p = __expf(S[qi][ji] - mnew);
        S[qi][ji] = p;
        psum += p;
      }
#pragma unroll
      for (int off = 1; off < 16; off <<= 1) psum += __shfl_xor(psum, off, 64);
      l[qi] = l[qi] * sc + psum;
      m[qi] = mnew;
#pragma unroll
      for (int di = 0; di < 4; di++) O[qi][di] *= sc;
    }

    __syncthreads();
#pragma unroll
    for (int qi = 0; qi < 4; qi++)
      *(float4*)&KP[(ty * 4 + qi) * LSTR + tx * 4] =
          make_float4(S[qi][0], S[qi][1], S[qi][2], S[qi][3]);
    __syncthreads();

#pragma unroll 4
    for (int j = 0; j < 64; j++) {
      float4 v4 = *(const float4*)&Vs[j * LSTR + tx * 4];
      float p0 = KP[(ty * 4 + 0) * LSTR + j];
      float p1 = KP[(ty * 4 + 1) * LSTR + j];
      float p2 = KP[(ty * 4 + 2) * LSTR + j];
      float p3 = KP[(ty * 4 + 3) * LSTR + j];
      O[0][0] = fmaf(p0, v4.x, O[0][0]); O[0][1] = fmaf(p0, v4.y, O[0][1]);
      O[0][2] = fmaf(p0, v4.z, O[0][2]); O[0][3] = fmaf(p0, v4.w, O[0][3]);
      O[1][0] = fmaf(p1, v4.x, O[1][0]); O[1][1] = fmaf(p1, v4.y, O[1][1]);
      O[1][2] = fmaf(p1, v4.z, O[1][2]); O[1][3] = fmaf(p1, v4.w, O[1][3]);
      O[2][0] = fmaf(p2, v4.x, O[2][0]); O[2][1] = fmaf(p2, v4.y, O[2][1]);
      O[2][2] = fmaf(p2, v4.z, O[2][2]); O[2][3] = fmaf(p2, v4.w, O[2][3]);
      O[3][0] = fmaf(p3, v4.x, O[3][0]); O[3][1] = fmaf(p3, v4.y, O[3][1]);
      O[3][2] = fmaf(p3, v4.z, O[3][2]); O[3][3] = fmaf(p3, v4.w, O[3][3]);
    }
  }

#pragma unroll
  for (int qi = 0; qi < 4; qi++) {
    float inv = 1.f / l[qi];
    float4 ov = make_float4(O[qi][0] * inv, O[qi][1] * inv, O[qi][2] * inv, O[qi][3] * inv);
    *(float4*)&o[(size_t)(b * TB + q0 + ty * 4 + qi) * CDIM + h * DHD + tx * 4] = ov;
  }
}

// ---------------- gate: logits, top-2, aux accumulators ----------------
__global__ __launch_bounds__(256) void gate_kernel(
    const float* __restrict__ xf, const float* __restrict__ gw,
    int* __restrict__ topidx, float* __restrict__ topw,
    int* __restrict__ counts, float* __restrict__ loadAcc, float* __restrict__ zAcc) {
  int wave = threadIdx.x >> 6, lane = threadIdx.x & 63;
  int n = blockIdx.x * 4 + wave;
  const float* xr = xf + (size_t)n * CDIM;
  float acc[NEXP];
#pragma unroll
  for (int e = 0; e < NEXP; e++) acc[e] = 0.f;
  for (int i = lane; i < CDIM; i += 64) {
    float xv = xr[i];
    const float* g = gw + (size_t)i * NEXP;
#pragma unroll
    for (int e = 0; e < NEXP; e++) acc[e] = fmaf(xv, g[e], acc[e]);
  }
#pragma unroll
  for (int e = 0; e < NEXP; e++) acc[e] = waveSum(acc[e]);
  __shared__ float sprob[4][NEXP];
  __shared__ float sz[4];
  if (lane == 0) {
    int i0 = 0; float v0 = acc[0];
#pragma unroll
    for (int e = 1; e < NEXP; e++) if (acc[e] > v0) { v0 = acc[e]; i0 = e; }
    int i1 = -1; float v1 = -1e30f;
#pragma unroll
    for (int e = 0; e < NEXP; e++) if (e != i0 && acc[e] > v1) { v1 = acc[e]; i1 = e; }
    float w0 = 1.f / (1.f + __expf(v1 - v0));
    topidx[n * 2] = i0; topidx[n * 2 + 1] = i1;
    topw[n * 2] = w0;  topw[n * 2 + 1] = 1.f - w0;
    atomicAdd(&counts[i0], 1);
    atomicAdd(&counts[i1], 1);
    float se = 0.f;
#pragma unroll
    for (int e = 0; e < NEXP; e++) se += __expf(acc[e] - v0);
    float inv = 1.f / se;
#pragma unroll
    for (int e = 0; e < NEXP; e++) sprob[wave][e] = __expf(acc[e] - v0) * inv;
    float lse = v0 + logf(se);
    sz[wave] = lse * lse;
  }
  __syncthreads();
  if (threadIdx.x < NEXP) {
    float s = sprob[0][threadIdx.x] + sprob[1][threadIdx.x] +
              sprob[2][threadIdx.x] + sprob[3][threadIdx.x];
    atomicAdd(&loadAcc[threadIdx.x], s);
  } else if (threadIdx.x == NEXP) {
    atomicAdd(zAcc, sz[0] + sz[1] + sz[2] + sz[3]);
  }
}

__global__ void prefix_kernel(const int* __restrict__ counts, int* __restrict__ offsets) {
  if (threadIdx.x == 0) {
    int s = 0;
    for (int e = 0; e < NEXP; e++) { offsets[e] = s; s += counts[e]; }
  }
}

__global__ __launch_bounds__(256) void scatter_kernel(
    const int* __restrict__ topidx, const float* __restrict__ topw,
    const int* __restrict__ offsets, int* __restrict__ cursors,
    int* __restrict__ assign_token, float* __restrict__ assign_w,
    int* __restrict__ token_slot) {
  int n = blockIdx.x * 256 + threadIdx.x;
  if (n >= NTOKS) return;
  for (int kk = 0; kk < 2; kk++) {
    int e = topidx[n * 2 + kk];
    int pos = atomicAdd(&cursors[e], 1);
    int slot = offsets[e] + pos;
    assign_token[slot] = n;
    assign_w[slot] = topw[n * 2 + kk];
    token_slot[n * 2 + kk] = slot;
  }
}

// ---------------- combine: out = h + alpha_moe*(shared + routed) ----------------
__global__ __launch_bounds__(256) void combine_kernel(
    const float* __restrict__ h, const float* __restrict__ shared_o,
    const float* __restrict__ abuf, const int* __restrict__ token_slot,
    const float* __restrict__ alphaPtr, float* __restrict__ out) {
  int i4 = blockIdx.x * 256 + threadIdx.x;
  int n = i4 >> 8;
  int cc = i4 & 255;
  float am = alphaPtr[0];
  int s0 = token_slot[n * 2], s1 = token_slot[n * 2 + 1];
  float4 hv = ((const float4*)h)[i4];
  float4 sv = ((const float4*)shared_o)[i4];
  float4 r0 = ((const float4*)abuf)[(size_t)s0 * 256 + cc];
  float4 r1 = ((const float4*)abuf)[(size_t)s1 * 256 + cc];
  float4 ov = make_float4(hv.x + am * (sv.x + r0.x + r1.x),
                          hv.y + am * (sv.y + r0.y + r1.y),
                          hv.z + am * (sv.z + r0.z + r1.z),
                          hv.w + am * (sv.w + r0.w + r1.w));
  ((float4*)out)[i4] = ov;
}

__global__ void finalize_kernel(const float* __restrict__ loadAcc,
                                const float* __restrict__ zAcc, float* __restrict__ outAux) {
  if (threadIdx.x == 0) {
    float s = 0.f;
    for (int e = 0; e < NEXP; e++) s += loadAcc[e];
    float lb = 0.f;
    for (int e = 0; e < NEXP; e++) { float f = loadAcc[e] / s; lb += f * f; }
    lb *= (float)NEXP;
    float z = zAcc[0] / (float)NTOKS;
    outAux[0] = 0.01f * lb + 0.001f * z;
  }
}

// ---------------- host orchestration ----------------
extern "C" void kernel_launch(void* const* d_in, const int* in_sizes, int n_in,
                              void* d_out, int out_size, void* d_ws, size_t ws_size,
                              hipStream_t stream) {
  const float* x   = (const float*)d_in[0];
  const float* ln1 = (const float*)d_in[1];
  const float* ln2 = (const float*)d_in[2];
  const float* wq  = (const float*)d_in[3];
  const float* wk  = (const float*)d_in[4];
  const float* wv  = (const float*)d_in[5];
  const float* wo  = (const float*)d_in[6];
  const float* sw1 = (const float*)d_in[7];
  const float* sw2 = (const float*)d_in[8];
  const float* sw3 = (const float*)d_in[9];
  const float* ew1 = (const float*)d_in[10];
  const float* ew2 = (const float*)d_in[11];
  const float* ew3 = (const float*)d_in[12];
  const float* gw  = (const float*)d_in[13];
  const float* aAttn = (const float*)d_in[14];
  const float* aMoe  = (const float*)d_in[15];

  float* ws = (float*)d_ws;
  float* xn   = ws; ws += (size_t)NTOKS * CDIM;        // xn1, later xf
  float* qkvb = ws; ws += (size_t)NTOKS * QKVD;        // packed q|k|v
  float* wpk  = ws; ws += (size_t)CDIM * QKVD;         // packed wq|wk|wv
  float* att  = ws; ws += (size_t)NTOKS * CDIM;        // attn out, later shared_out
  float* hb   = ws; ws += (size_t)NTOKS * CDIM;
  float* mid  = ws; ws += (size_t)2 * NTOKS * FFD;     // 8192 x 4096
  float* abuf = ws; ws += (size_t)2 * NTOKS * CDIM;    // 8192 x 1024
  int* ctl = (int*)ws;
  int* counts  = ctl;        // 8
  int* cursors = ctl + 8;    // 8
  float* loadAcc = (float*)(ctl + 16);  // 8
  float* zAcc = loadAcc + 8;            // 1
  int* offsets = ctl + 25;   // 8
  int* topidx = ctl + 33;            // 8192
  int* assign_token = topidx + 8192; // 8192
  int* token_slot = assign_token + 8192;  // 8192
  float* topw = (float*)(token_slot + 8192);  // 8192
  float* assign_w = topw + 8192;              // 8192

  hipMemsetAsync(counts, 0, 25 * sizeof(int), stream);

  // 1) rmsnorm1
  rmsnorm_kernel<<<NTOKS, 256, 0, stream>>>(x, ln1, xn);
  // 2) fused QKV projection (N=1536) into packed buffer
  packqkv_kernel<<<CDIM, 256, 0, stream>>>(wq, wk, wv, wpk);
  gemm_kernel<0><<<dim3(12, 32), 256, 0, stream>>>(xn, wpk, qkvb, NTOKS, QKVD, CDIM,
      nullptr, nullptr, nullptr, 0, nullptr, nullptr, nullptr);
  // 3) RoPE
  rope_kernel<<<(NTOKS * NH * 32 + NTOKS * NKV * 32) / 256, 256, 0, stream>>>(qkvb);
  // 4) attention (flash-style tiled)
  attn_kernel<<<1024, 256, 0, stream>>>(qkvb, att);
  // 5) wo projection + ReZero residual: h = x + alpha_attn * (att @ wo)
  gemm_kernel<2><<<dim3(8, 32), 256, 0, stream>>>(att, wo, hb, NTOKS, 1024, 1024,
      nullptr, nullptr, nullptr, 0, x, aAttn, nullptr);
  // 6) rmsnorm2 -> xf (reuse xn)
  rmsnorm_kernel<<<NTOKS, 256, 0, stream>>>(hb, ln2, xn);
  // 7) shared expert SwiGLU: fused up, then down -> att (reused as shared_out)
  gemm_up_kernel<<<dim3(64, 32), 256, 0, stream>>>(xn, sw1, sw2, mid, NTOKS,
      nullptr, nullptr, nullptr, 0);
  gemm_kernel<0><<<dim3(8, 32), 256, 0, stream>>>(mid, sw3, att, NTOKS, CDIM, FFD,
      nullptr, nullptr, nullptr, 0, nullptr, nullptr, nullptr);
  // 8) routing
  gate_kernel<<<NTOKS / 4, 256, 0, stream>>>(xn, gw, topidx, topw, counts, loadAcc, zAcc);
  prefix_kernel<<<1, 64, 0, stream>>>(counts, offsets);
  scatter_kernel<<<NTOKS / 256, 256, 0, stream>>>(topidx, topw, offsets, cursors,
                                                  assign_token, assign_w, token_slot);
  // 9) routed experts, ALL experts in one launch via gridDim.z
  gemm_up_kernel<<<dim3(64, 32, NEXP), 256, 0, stream>>>(xn, ew1, ew2, mid, 0,
      assign_token, offsets, counts, (size_t)CDIM * FFD);
  gemm_kernel<3><<<dim3(8, 32, NEXP), 256, 0, stream>>>(mid, ew3, abuf, 0, CDIM, FFD,
      nullptr, offsets, counts, (size_t)FFD * CDIM, nullptr, nullptr, assign_w);
  // 10) combine + aux
  combine_kernel<<<NTOKS * CDIM / 4 / 256, 256, 0, stream>>>(hb, att, abuf, token_slot,
                                                             aMoe, (float*)d_out);
  finalize_kernel<<<1, 64, 0, stream>>>(loadAcc, zAcc, (float*)d_out + (size_t)NTOKS * CDIM);
}

// Round 2
// 1722.247 us; speedup vs baseline: 5.7397x; 2.9013x over previous
//
#include <hip/hip_runtime.h>
#include <math.h>

// ---------------- problem constants ----------------
#define TB    2048      // T
#define CDIM  1024      // C
#define NTOKS 4096      // B*T
#define NH    16
#define NKV   4
#define DHD   64
#define FFD   4096
#define NEXP  8
#define WINSZ 1024
#define QKVD  1536      // packed q(1024)+k(256)+v(256) row stride
#define KOFS  1024
#define VOFS  1280

typedef unsigned short u16;
typedef unsigned int   u32;
typedef __attribute__((ext_vector_type(8))) short short8;   // 8 bf16 (4 VGPRs)
typedef __attribute__((ext_vector_type(4))) float f32x4;    // MFMA acc

// ---------------- helpers ----------------
__device__ __forceinline__ float waveSum(float v) {
#pragma unroll
  for (int o = 32; o; o >>= 1) v += __shfl_xor(v, o, 64);
  return v;
}

__device__ __forceinline__ u16 f2bf(float f) {  // RNE f32->bf16
  u32 u = __float_as_uint(f);
  u += 0x7fffu + ((u >> 16) & 1u);
  return (u16)(u >> 16);
}

__device__ __forceinline__ u32 pkbf(float lo, float hi) {  // [bf(lo) | bf(hi)<<16]
  u32 a = __float_as_uint(lo); a += 0x7fffu + ((a >> 16) & 1u);
  u32 b = __float_as_uint(hi); b += 0x7fffu + ((b >> 16) & 1u);
  return (a >> 16) | (b & 0xffff0000u);
}

// ---------------- RMSNorm: one block per token row; writes f32 + bf16 ----------------
__global__ __launch_bounds__(256) void rmsnorm_kernel(
    const float* __restrict__ x, const float* __restrict__ w,
    float* __restrict__ o, u16* __restrict__ ob) {
  int n = blockIdx.x;
  const float* xr = x + (size_t)n * CDIM;
  float s = 0.f;
  for (int i = threadIdx.x; i < CDIM; i += 256) { float v = xr[i]; s += v * v; }
  s = waveSum(s);
  __shared__ float sm[4];
  if ((threadIdx.x & 63) == 0) sm[threadIdx.x >> 6] = s;
  __syncthreads();
  float tot = sm[0] + sm[1] + sm[2] + sm[3];
  float r = rsqrtf(tot * (1.f / CDIM) + 1e-6f);
  float* orow = o + (size_t)n * CDIM;
  u16* obrow = ob + (size_t)n * CDIM;
  for (int i = threadIdx.x; i < CDIM; i += 256) {
    float v = xr[i] * r * w[i];
    orow[i] = v;
    obrow[i] = f2bf(v);
  }
}

// ---------------- pack wq|wk|wv into f32 [C][1536] ----------------
__global__ __launch_bounds__(256) void packqkv_kernel(
    const float* __restrict__ wq, const float* __restrict__ wk,
    const float* __restrict__ wv, float* __restrict__ wp) {
  int c = blockIdx.x;  // 0..1023
  for (int j = threadIdx.x; j < QKVD; j += 256) {
    float v;
    if (j < 1024)      v = wq[(size_t)c * 1024 + j];
    else if (j < 1280) v = wk[(size_t)c * 256 + (j - 1024)];
    else               v = wv[(size_t)c * 256 + (j - 1280)];
    wp[(size_t)c * QKVD + j] = v;
  }
}

// ---------------- bf16 MFMA GEMM ----------------
// C[m][n] = sum_k A[m][k]*B[k][n].  A: bf16 [rows][Kd] (global, row-major).
// B: f32 [Kd][Nn] (global, row-major) -> converted+transposed to LDS bf16 [n][k].
// Tile: BM=128 x (NMATS==1 ? 128 : 2x64), BK=32. 4 waves (2x2), wave tile 64x(64|32 per mat).
// OP: 0 = store f32; 2 = Dres + alpha*acc (f32); 3 = acc*rowScale (f32);
//     4 = silu(acc0)*acc1 -> bf16 (requires NMATS==2).
// gridDim.z = expert: B += z*bStride; rows from ofsPtr/cntPtr[z].
#define LDA 40   // LDS row stride in bf16 (32 data + 8 pad = 80B)

template <int OP, int NMATS, bool GATHER>
__global__ __launch_bounds__(256) void mgemm(
    const u16* __restrict__ A, const float* __restrict__ B0g, const float* __restrict__ B1g,
    float* __restrict__ Cf, u16* __restrict__ Cb,
    int M, int Nn, int Kd,
    const int* __restrict__ rowIdx, const int* __restrict__ ofsPtr,
    const int* __restrict__ cntPtr, size_t bStride,
    const float* __restrict__ Dres, const float* __restrict__ alphaPtr,
    const float* __restrict__ rowScale, int ldc) {
  const int BN = (NMATS == 1) ? 128 : 64;   // per-matrix col-tile
  const int CW = (NMATS == 1) ? 64 : 32;    // wave col extent per matrix
  const int NF = (NMATS == 1) ? 4 : 2;      // n-frags per matrix

  int e = blockIdx.z;
  int ofs = ofsPtr ? ofsPtr[e] : 0;
  int Mloc = cntPtr ? cntPtr[e] : M;
  int rowTile = blockIdx.y * 128;
  if (rowTile >= Mloc) return;
  int colTile = blockIdx.x * BN;
  const float* B0 = B0g + (size_t)e * bStride;
  const float* B1 = (NMATS == 2) ? (B1g + (size_t)e * bStride) : nullptr;

  __shared__ u16 As[128 * LDA];
  __shared__ u16 Bs[128 * LDA];   // NMATS==2: rows 0..63 = mat0, 64..127 = mat1

  int tid = threadIdx.x;
  int lane = tid & 63;
  int w = tid >> 6;
  int wr = w >> 1, wc = w & 1;

  // ---- A staging: 512 chunks of 8 bf16; thread owns chunks tid, tid+256 ----
  int arow0 = tid >> 2, k80 = tid & 3;
  int arow1 = arow0 + 64;
  const u16* apt0;
  const u16* apt1;
  {
    int g0 = rowTile + arow0, g1 = rowTile + arow1;
    int r0, r1;
    if (GATHER) {
      r0 = (g0 < Mloc) ? rowIdx[ofs + g0] : 0;
      r1 = (g1 < Mloc) ? rowIdx[ofs + g1] : 0;
    } else if (ofsPtr) {
      r0 = (g0 < Mloc) ? (ofs + g0) : 0;
      r1 = (g1 < Mloc) ? (ofs + g1) : 0;
    } else { r0 = g0; r1 = g1; }
    apt0 = A + (size_t)r0 * Kd + k80 * 8;
    apt1 = A + (size_t)r1 * Kd + k80 * 8;
  }

  // ---- B staging slots: slot covers 4 n x 2 k (pack k,k+1 into dwords) ----
  int np0, kp0, np1, kp1;
  if (NMATS == 1) { np0 = tid & 31; kp0 = tid >> 5; np1 = (tid + 256) & 31; kp1 = (tid + 256) >> 5; }
  else            { np0 = tid & 15; kp0 = tid >> 4; np1 = 0; kp1 = 0; }
  const float* bp0 = B0 + (size_t)(2 * kp0) * Nn + colTile + np0 * 4;
  const float* bp1 = (NMATS == 1) ? (B0 + (size_t)(2 * kp1) * Nn + colTile + np1 * 4)
                                  : (B1 + (size_t)(2 * kp0) * Nn + colTile + np0 * 4);

  f32x4 acc[4][4];
#pragma unroll
  for (int i = 0; i < 4; i++)
#pragma unroll
    for (int j = 0; j < 4; j++) acc[i][j] = (f32x4){0.f, 0.f, 0.f, 0.f};

  int nsteps = Kd >> 5;
  // prologue loads (tile 0)
  short8 a0r = *(const short8*)apt0;
  short8 a1r = *(const short8*)apt1;
  float4 q0a = *(const float4*)bp0;
  float4 q0b = *(const float4*)(bp0 + Nn);
  float4 q1a = *(const float4*)bp1;
  float4 q1b = *(const float4*)(bp1 + Nn);

  int abase = (wr * 64 + (lane & 15)) * LDA + (lane >> 4) * 8;
  int bbase = (wc * CW + (lane & 15)) * LDA + (lane >> 4) * 8;

  for (int t = 0; t < nsteps; ++t) {
    __syncthreads();  // prior reads done
    // store staged tile
    *(short8*)&As[arow0 * LDA + k80 * 8] = a0r;
    *(short8*)&As[arow1 * LDA + k80 * 8] = a1r;
    {
      u32 d0 = pkbf(q0a.x, q0b.x), d1 = pkbf(q0a.y, q0b.y);
      u32 d2 = pkbf(q0a.z, q0b.z), d3 = pkbf(q0a.w, q0b.w);
      int nb = np0 * 4;
      *(u32*)&Bs[(nb + 0) * LDA + 2 * kp0] = d0;
      *(u32*)&Bs[(nb + 1) * LDA + 2 * kp0] = d1;
      *(u32*)&Bs[(nb + 2) * LDA + 2 * kp0] = d2;
      *(u32*)&Bs[(nb + 3) * LDA + 2 * kp0] = d3;
      u32 e0 = pkbf(q1a.x, q1b.x), e1 = pkbf(q1a.y, q1b.y);
      u32 e2 = pkbf(q1a.z, q1b.z), e3 = pkbf(q1a.w, q1b.w);
      if (NMATS == 1) {
        int nb1 = np1 * 4;
        *(u32*)&Bs[(nb1 + 0) * LDA + 2 * kp1] = e0;
        *(u32*)&Bs[(nb1 + 1) * LDA + 2 * kp1] = e1;
        *(u32*)&Bs[(nb1 + 2) * LDA + 2 * kp1] = e2;
        *(u32*)&Bs[(nb1 + 3) * LDA + 2 * kp1] = e3;
      } else {
        *(u32*)&Bs[64 * LDA + (nb + 0) * LDA + 2 * kp0] = e0;
        *(u32*)&Bs[64 * LDA + (nb + 1) * LDA + 2 * kp0] = e1;
        *(u32*)&Bs[64 * LDA + (nb + 2) * LDA + 2 * kp0] = e2;
        *(u32*)&Bs[64 * LDA + (nb + 3) * LDA + 2 * kp0] = e3;
      }
    }
    // prefetch next tile (flies under the MFMA phase)
    if (t + 1 < nsteps) {
      size_t ao = (size_t)(t + 1) * 32;
      a0r = *(const short8*)(apt0 + ao);
      a1r = *(const short8*)(apt1 + ao);
      size_t bo = (size_t)(t + 1) * 32 * Nn;
      q0a = *(const float4*)(bp0 + bo);
      q0b = *(const float4*)(bp0 + bo + Nn);
      q1a = *(const float4*)(bp1 + bo);
      q1b = *(const float4*)(bp1 + bo + Nn);
    }
    __syncthreads();  // tile visible

    short8 af[4];
#pragma unroll
    for (int i = 0; i < 4; i++) af[i] = *(const short8*)&As[abase + i * 16 * LDA];
    if (NMATS == 1) {
      short8 bfv[4];
#pragma unroll
      for (int j = 0; j < 4; j++) bfv[j] = *(const short8*)&Bs[bbase + j * 16 * LDA];
#pragma unroll
      for (int i = 0; i < 4; i++)
#pragma unroll
        for (int j = 0; j < 4; j++)
          acc[i][j] = __builtin_amdgcn_mfma_f32_16x16x32_bf16(af[i], bfv[j], acc[i][j], 0, 0, 0);
    } else {
      short8 b0v[2], b1v[2];
#pragma unroll
      for (int j = 0; j < 2; j++) {
        b0v[j] = *(const short8*)&Bs[bbase + j * 16 * LDA];
        b1v[j] = *(const short8*)&Bs[64 * LDA + bbase + j * 16 * LDA];
      }
#pragma unroll
      for (int i = 0; i < 4; i++)
#pragma unroll
        for (int j = 0; j < 2; j++) {
          acc[i][j]     = __builtin_amdgcn_mfma_f32_16x16x32_bf16(af[i], b0v[j], acc[i][j], 0, 0, 0);
          acc[i][j + 2] = __builtin_amdgcn_mfma_f32_16x16x32_bf16(af[i], b1v[j], acc[i][j + 2], 0, 0, 0);
        }
    }
  }

  // ---- epilogue ----
  int crowBase = ofsPtr ? ofs : 0;
  float al = (OP == 2) ? alphaPtr[0] : 0.f;
  if (OP == 4) {
#pragma unroll
    for (int i = 0; i < 4; i++)
#pragma unroll
      for (int j = 0; j < 2; j++) {
        f32x4 a1v = acc[i][j];
        f32x4 a2v = acc[i][j + 2];
#pragma unroll
        for (int r = 0; r < 4; r++) {
          int grow = rowTile + wr * 64 + i * 16 + (lane >> 4) * 4 + r;
          if (grow < Mloc) {
            int col = colTile + wc * 32 + j * 16 + (lane & 15);
            float h1 = a1v[r], h2 = a2v[r];
            float val = (h1 / (1.f + __expf(-h1))) * h2;
            Cb[(size_t)(crowBase + grow) * ldc + col] = f2bf(val);
          }
        }
      }
  } else {
#pragma unroll
    for (int i = 0; i < 4; i++)
#pragma unroll
      for (int j = 0; j < NF; j++) {
#pragma unroll
        for (int r = 0; r < 4; r++) {
          int grow = rowTile + wr * 64 + i * 16 + (lane >> 4) * 4 + r;
          if (grow < Mloc) {
            int col = colTile + wc * CW + j * 16 + (lane & 15);
            size_t ci = (size_t)(crowBase + grow) * ldc + col;
            float v = acc[i][j][r];
            if (OP == 0)      Cf[ci] = v;
            else if (OP == 2) Cf[ci] = Dres[ci] + al * v;
            else              Cf[ci] = v * rowScale[ofs + grow];
          }
        }
      }
  }
}

// ---------------- RoPE (in-place on packed qkv buffer) ----------------
__device__ __forceinline__ void rope_one(float* row, int t, int j) {
  float invf = __expf(-(float)j * (9.210340371976184f / 32.f));  // ln(10000)/32
  float ang = (float)t * invf;
  float c = cosf(ang), s = sinf(ang);
  float u0 = row[j], u1 = row[j + 32];
  row[j] = u0 * c - u1 * s;
  row[j + 32] = u1 * c + u0 * s;
}

__global__ __launch_bounds__(256) void rope_kernel(float* __restrict__ qkv) {
  int gid = blockIdx.x * 256 + threadIdx.x;
  const int QN = NTOKS * NH * 32;
  const int KN = NTOKS * NKV * 32;
  if (gid < QN) {
    int j = gid & 31;
    int h = (gid >> 5) & (NH - 1);
    int n = gid >> 9;
    rope_one(qkv + (size_t)n * QKVD + h * DHD, n & (TB - 1), j);
  } else if (gid < QN + KN) {
    int g2 = gid - QN;
    int j = g2 & 31;
    int g = (g2 >> 5) & (NKV - 1);
    int n = g2 >> 7;
    rope_one(qkv + (size_t)n * QKVD + KOFS + g * DHD, n & (TB - 1), j);
  }
}

// ---------------- flash attention: one block per (b, h, 64-query tile) ----------------
#define LSTR 68

__global__ __launch_bounds__(256) void attn_kernel(
    const float* __restrict__ qkv, u16* __restrict__ o) {
  __shared__ float Qs[64 * LSTR];
  __shared__ float KP[64 * LSTR];
  __shared__ float Vs[64 * LSTR];

  int tid = threadIdx.x;
  int tx = tid & 15, ty = tid >> 4;
  int qt = blockIdx.x & 31;
  int h = (blockIdx.x >> 5) & (NH - 1);
  int b = blockIdx.x >> 9;
  int g = h >> 2;  // kv group (NREP=4)
  int q0 = qt * 64;

#pragma unroll
  for (int i = 0; i < 4; i++) {
    int slot = tid + 256 * i;
    int r = slot >> 4, c = (slot & 15) * 4;
    float4 qv = *(const float4*)&qkv[(size_t)(b * TB + q0 + r) * QKVD + h * DHD + c];
    *(float4*)&Qs[r * LSTR + c] = qv;
  }

  float O[4][4], S[4][4], m[4], l[4];
#pragma unroll
  for (int i = 0; i < 4; i++) {
    m[i] = -1e30f; l[i] = 0.f;
#pragma unroll
    for (int j = 0; j < 4; j++) O[i][j] = 0.f;
  }

  int kt0 = q0 - WINSZ; if (kt0 < 0) kt0 = 0;
  for (int kt = kt0; kt <= q0; kt += 64) {
    __syncthreads();  // prev PV done
#pragma unroll
    for (int i = 0; i < 4; i++) {
      int slot = tid + 256 * i;
      int r = slot >> 4, c = (slot & 15) * 4;
      const float* krow = &qkv[(size_t)(b * TB + kt + r) * QKVD + KOFS + g * DHD + c];
      float4 kv = *(const float4*)krow;
      KP[(c + 0) * LSTR + r] = kv.x;
      KP[(c + 1) * LSTR + r] = kv.y;
      KP[(c + 2) * LSTR + r] = kv.z;
      KP[(c + 3) * LSTR + r] = kv.w;
      const float* vrow = &qkv[(size_t)(b * TB + kt + r) * QKVD + VOFS + g * DHD + c];
      *(float4*)&Vs[r * LSTR + c] = *(const float4*)vrow;
    }
    __syncthreads();

#pragma unroll
    for (int i = 0; i < 4; i++)
#pragma unroll
      for (int j = 0; j < 4; j++) S[i][j] = 0.f;
#pragma unroll 4
    for (int d = 0; d < 64; d++) {
      float4 k4 = *(const float4*)&KP[d * LSTR + tx * 4];
      float q0v = Qs[(ty * 4 + 0) * LSTR + d];
      float q1v = Qs[(ty * 4 + 1) * LSTR + d];
      float q2v = Qs[(ty * 4 + 2) * LSTR + d];
      float q3v = Qs[(ty * 4 + 3) * LSTR + d];
      S[0][0] = fmaf(q0v, k4.x, S[0][0]); S[0][1] = fmaf(q0v, k4.y, S[0][1]);
      S[0][2] = fmaf(q0v, k4.z, S[0][2]); S[0][3] = fmaf(q0v, k4.w, S[0][3]);
      S[1][0] = fmaf(q1v, k4.x, S[1][0]); S[1][1] = fmaf(q1v, k4.y, S[1][1]);
      S[1][2] = fmaf(q1v, k4.z, S[1][2]); S[1][3] = fmaf(q1v, k4.w, S[1][3]);
      S[2][0] = fmaf(q2v, k4.x, S[2][0]); S[2][1] = fmaf(q2v, k4.y, S[2][1]);
      S[2][2] = fmaf(q2v, k4.z, S[2][2]); S[2][3] = fmaf(q2v, k4.w, S[2][3]);
      S[3][0] = fmaf(q3v, k4.x, S[3][0]); S[3][1] = fmaf(q3v, k4.y, S[3][1]);
      S[3][2] = fmaf(q3v, k4.z, S[3][2]); S[3][3] = fmaf(q3v, k4.w, S[3][3]);
    }

    int maskDiag = (kt == q0);
    int maskEdge = (kt == q0 - WINSZ);
#pragma unroll
    for (int qi = 0; qi < 4; qi++) {
      int qg = q0 + ty * 4 + qi;
#pragma unroll
      for (int ji = 0; ji < 4; ji++) {
        int kj = kt + tx * 4 + ji;
        float s = S[qi][ji] * 0.125f;  // 1/sqrt(64)
        if (maskDiag && kj > qg) s = -1e30f;
        if (maskEdge && kj < qg - WINSZ) s = -1e30f;
        S[qi][ji] = s;
      }
      float mloc = fmaxf(fmaxf(S[qi][0], S[qi][1]), fmaxf(S[qi][2], S[qi][3]));
#pragma unroll
      for (int off = 1; off < 16; off <<= 1) mloc = fmaxf(mloc, __shfl_xor(mloc, off, 64));
      float mnew = fmaxf(m[qi], mloc);
      float sc = __expf(m[qi] - mnew);
      float psum = 0.f;
#pragma unroll
      for (int ji = 0; ji < 4; ji++) {
        float p = __expf(S[qi][ji] - mnew);
        S[qi][ji] = p;
        psum += p;
      }
#pragma unroll
      for (int off = 1; off < 16; off <<= 1) psum += __shfl_xor(psum, off, 64);
      l[qi] = l[qi] * sc + psum;
      m[qi] = mnew;
#pragma unroll
      for (int di = 0; di < 4; di++) O[qi][di] *= sc;
    }

    __syncthreads();
#pragma unroll
    for (int qi = 0; qi < 4; qi++)
      *(float4*)&KP[(ty * 4 + qi) * LSTR + tx * 4] =
          make_float4(S[qi][0], S[qi][1], S[qi][2], S[qi][3]);
    __syncthreads();

#pragma unroll 4
    for (int j = 0; j < 64; j++) {
      float4 v4 = *(const float4*)&Vs[j * LSTR + tx * 4];
      float p0 = KP[(ty * 4 + 0) * LSTR + j];
      float p1 = KP[(ty * 4 + 1) * LSTR + j];
      float p2 = KP[(ty * 4 + 2) * LSTR + j];
      float p3 = KP[(ty * 4 + 3) * LSTR + j];
      O[0][0] = fmaf(p0, v4.x, O[0][0]); O[0][1] = fmaf(p0, v4.y, O[0][1]);
      O[0][2] = fmaf(p0, v4.z, O[0][2]); O[0][3] = fmaf(p0, v4.w, O[0][3]);
      O[1][0] = fmaf(p1, v4.x, O[1][0]); O[1][1] = fmaf(p1, v4.y, O[1][1]);
      O[1][2] = fmaf(p1, v4.z, O[1][2]); O[1][3] = fmaf(p1, v4.w, O[1][3]);
      O[2][0] = fmaf(p2, v4.x, O[2][0]); O[2][1] = fmaf(p2, v4.y, O[2][1]);
      O[2][2] = fmaf(p2, v4.z, O[2][2]); O[2][3] = fmaf(p2, v4.w, O[2][3]);
      O[3][0] = fmaf(p3, v4.x, O[3][0]); O[3][1] = fmaf(p3, v4.y, O[3][1]);
      O[3][2] = fmaf(p3, v4.z, O[3][2]); O[3][3] = fmaf(p3, v4.w, O[3][3]);
    }
  }

#pragma unroll
  for (int qi = 0; qi < 4; qi++) {
    float inv = 1.f / l[qi];
    ushort4 ov;
    ov.x = f2bf(O[qi][0] * inv);
    ov.y = f2bf(O[qi][1] * inv);
    ov.z = f2bf(O[qi][2] * inv);
    ov.w = f2bf(O[qi][3] * inv);
    *(ushort4*)&o[(size_t)(b * TB + q0 + ty * 4 + qi) * CDIM + h * DHD + tx * 4] = ov;
  }
}

// ---------------- gate: logits, top-2, aux accumulators ----------------
__global__ __launch_bounds__(256) void gate_kernel(
    const float* __restrict__ xf, const float* __restrict__ gw,
    int* __restrict__ topidx, float* __restrict__ topw,
    int* __restrict__ counts, float* __restrict__ loadAcc, float* __restrict__ zAcc) {
  int wave = threadIdx.x >> 6, lane = threadIdx.x & 63;
  int n = blockIdx.x * 4 + wave;
  const float* xr = xf + (size_t)n * CDIM;
  float acc[NEXP];
#pragma unroll
  for (int e = 0; e < NEXP; e++) acc[e] = 0.f;
  for (int i = lane; i < CDIM; i += 64) {
    float xv = xr[i];
    const float* g = gw + (size_t)i * NEXP;
#pragma unroll
    for (int e = 0; e < NEXP; e++) acc[e] = fmaf(xv, g[e], acc[e]);
  }
#pragma unroll
  for (int e = 0; e < NEXP; e++) acc[e] = waveSum(acc[e]);
  __shared__ float sprob[4][NEXP];
  __shared__ float sz[4];
  if (lane == 0) {
    int i0 = 0; float v0 = acc[0];
#pragma unroll
    for (int e = 1; e < NEXP; e++) if (acc[e] > v0) { v0 = acc[e]; i0 = e; }
    int i1 = -1; float v1 = -1e30f;
#pragma unroll
    for (int e = 0; e < NEXP; e++) if (e != i0 && acc[e] > v1) { v1 = acc[e]; i1 = e; }
    float w0 = 1.f / (1.f + __expf(v1 - v0));
    topidx[n * 2] = i0; topidx[n * 2 + 1] = i1;
    topw[n * 2] = w0;  topw[n * 2 + 1] = 1.f - w0;
    atomicAdd(&counts[i0], 1);
    atomicAdd(&counts[i1], 1);
    float se = 0.f;
#pragma unroll
    for (int e = 0; e < NEXP; e++) se += __expf(acc[e] - v0);
    float inv = 1.f / se;
#pragma unroll
    for (int e = 0; e < NEXP; e++) sprob[wave][e] = __expf(acc[e] - v0) * inv;
    float lse = v0 + logf(se);
    sz[wave] = lse * lse;
  }
  __syncthreads();
  if (threadIdx.x < NEXP) {
    float s = sprob[0][threadIdx.x] + sprob[1][threadIdx.x] +
              sprob[2][threadIdx.x] + sprob[3][threadIdx.x];
    atomicAdd(&loadAcc[threadIdx.x], s);
  } else if (threadIdx.x == NEXP) {
    atomicAdd(zAcc, sz[0] + sz[1] + sz[2] + sz[3]);
  }
}

__global__ void prefix_kernel(const int* __restrict__ counts, int* __restrict__ offsets) {
  if (threadIdx.x == 0) {
    int s = 0;
    for (int e = 0; e < NEXP; e++) { offsets[e] = s; s += counts[e]; }
  }
}

__global__ __launch_bounds__(256) void scatter_kernel(
    const int* __restrict__ topidx, const float* __restrict__ topw,
    const int* __restrict__ offsets, int* __restrict__ cursors,
    int* __restrict__ assign_token, float* __restrict__ assign_w,
    int* __restrict__ token_slot) {
  int n = blockIdx.x * 256 + threadIdx.x;
  if (n >= NTOKS) return;
  for (int kk = 0; kk < 2; kk++) {
    int e = topidx[n * 2 + kk];
    int pos = atomicAdd(&cursors[e], 1);
    int slot = offsets[e] + pos;
    assign_token[slot] = n;
    assign_w[slot] = topw[n * 2 + kk];
    token_slot[n * 2 + kk] = slot;
  }
}

// ---------------- combine: out = h + alpha_moe*(shared + routed) ----------------
__global__ __launch_bounds__(256) void combine_kernel(
    const float* __restrict__ h, const float* __restrict__ shared_o,
    const float* __restrict__ abuf, const int* __restrict__ token_slot,
    const float* __restrict__ alphaPtr, float* __restrict__ out) {
  int i4 = blockIdx.x * 256 + threadIdx.x;
  int n = i4 >> 8;
  int cc = i4 & 255;
  float am = alphaPtr[0];
  int s0 = token_slot[n * 2], s1 = token_slot[n * 2 + 1];
  float4 hv = ((const float4*)h)[i4];
  float4 sv = ((const float4*)shared_o)[i4];
  float4 r0 = ((const float4*)abuf)[(size_t)s0 * 256 + cc];
  float4 r1 = ((const float4*)abuf)[(size_t)s1 * 256 + cc];
  float4 ov = make_float4(hv.x + am * (sv.x + r0.x + r1.x),
                          hv.y + am * (sv.y + r0.y + r1.y),
                          hv.z + am * (sv.z + r0.z + r1.z),
                          hv.w + am * (sv.w + r0.w + r1.w));
  ((float4*)out)[i4] = ov;
}

__global__ void finalize_kernel(const float* __restrict__ loadAcc,
                                const float* __restrict__ zAcc, float* __restrict__ outAux) {
  if (threadIdx.x == 0) {
    float s = 0.f;
    for (int e = 0; e < NEXP; e++) s += loadAcc[e];
    float lb = 0.f;
    for (int e = 0; e < NEXP; e++) { float f = loadAcc[e] / s; lb += f * f; }
    lb *= (float)NEXP;
    float z = zAcc[0] / (float)NTOKS;
    outAux[0] = 0.01f * lb + 0.001f * z;
  }
}

// ---------------- host orchestration ----------------
extern "C" void kernel_launch(void* const* d_in, const int* in_sizes, int n_in,
                              void* d_out, int out_size, void* d_ws, size_t ws_size,
                              hipStream_t stream) {
  const float* x   = (const float*)d_in[0];
  const float* ln1 = (const float*)d_in[1];
  const float* ln2 = (const float*)d_in[2];
  const float* wq  = (const float*)d_in[3];
  const float* wk  = (const float*)d_in[4];
  const float* wv  = (const float*)d_in[5];
  const float* wo  = (const float*)d_in[6];
  const float* sw1 = (const float*)d_in[7];
  const float* sw2 = (const float*)d_in[8];
  const float* sw3 = (const float*)d_in[9];
  const float* ew1 = (const float*)d_in[10];
  const float* ew2 = (const float*)d_in[11];
  const float* ew3 = (const float*)d_in[12];
  const float* gw  = (const float*)d_in[13];
  const float* aAttn = (const float*)d_in[14];
  const float* aMoe  = (const float*)d_in[15];

  float* ws = (float*)d_ws;
  float* xn   = ws; ws += (size_t)NTOKS * CDIM;        // f32 normed (for gate)
  float* qkvb = ws; ws += (size_t)NTOKS * QKVD;        // f32 packed q|k|v
  float* wpk  = ws; ws += (size_t)CDIM * QKVD;         // f32 packed wq|wk|wv
  float* hb   = ws; ws += (size_t)NTOKS * CDIM;        // residual h
  float* sho  = ws; ws += (size_t)NTOKS * CDIM;        // shared expert out
  float* abuf = ws; ws += (size_t)2 * NTOKS * CDIM;    // routed out (slots)
  u16* xnb  = (u16*)ws; ws += (size_t)NTOKS * CDIM / 2;      // bf16 normed
  u16* attb = (u16*)ws; ws += (size_t)NTOKS * CDIM / 2;      // bf16 attn out
  u16* mids = (u16*)ws; ws += (size_t)NTOKS * FFD / 2;       // bf16 shared mid
  u16* midr = (u16*)ws; ws += (size_t)2 * NTOKS * FFD / 2;   // bf16 routed mid
  int* ctl = (int*)ws;
  int* counts  = ctl;        // 8
  int* cursors = ctl + 8;    // 8
  float* loadAcc = (float*)(ctl + 16);  // 8
  float* zAcc = loadAcc + 8;            // 1
  int* offsets = ctl + 25;   // 8
  int* topidx = ctl + 33;            // 8192
  int* assign_token = topidx + 8192; // 8192
  int* token_slot = assign_token + 8192;  // 8192
  float* topw = (float*)(token_slot + 8192);  // 8192
  float* assign_w = topw + 8192;              // 8192

  hipMemsetAsync(counts, 0, 25 * sizeof(int), stream);

  // 1) rmsnorm1 -> xn (f32) + xnb (bf16)
  rmsnorm_kernel<<<NTOKS, 256, 0, stream>>>(x, ln1, xn, xnb);
  // 2) fused QKV projection (N=1536, bf16 MFMA)
  packqkv_kernel<<<CDIM, 256, 0, stream>>>(wq, wk, wv, wpk);
  mgemm<0, 1, false><<<dim3(12, 32), 256, 0, stream>>>(
      xnb, wpk, nullptr, qkvb, nullptr, NTOKS, QKVD, CDIM,
      nullptr, nullptr, nullptr, 0, nullptr, nullptr, nullptr, QKVD);
  // 3) RoPE
  rope_kernel<<<(NTOKS * NH * 32 + NTOKS * NKV * 32) / 256, 256, 0, stream>>>(qkvb);
  // 4) attention -> attb (bf16)
  attn_kernel<<<1024, 256, 0, stream>>>(qkvb, attb);
  // 5) wo projection + ReZero residual: h = x + alpha_attn * (att @ wo)
  mgemm<2, 1, false><<<dim3(8, 32), 256, 0, stream>>>(
      attb, wo, nullptr, hb, nullptr, NTOKS, CDIM, CDIM,
      nullptr, nullptr, nullptr, 0, x, aAttn, nullptr, CDIM);
  // 6) rmsnorm2 -> xn (f32 for gate) + xnb (bf16 for experts)
  rmsnorm_kernel<<<NTOKS, 256, 0, stream>>>(hb, ln2, xn, xnb);
  // 7) shared expert SwiGLU: fused up (bf16 mid), then down
  mgemm<4, 2, false><<<dim3(64, 32), 256, 0, stream>>>(
      xnb, sw1, sw2, nullptr, mids, NTOKS, FFD, CDIM,
      nullptr, nullptr, nullptr, 0, nullptr, nullptr, nullptr, FFD);
  mgemm<0, 1, false><<<dim3(8, 32), 256, 0, stream>>>(
      mids, sw3, nullptr, sho, nullptr, NTOKS, CDIM, FFD,
      nullptr, nullptr, nullptr, 0, nullptr, nullptr, nullptr, CDIM);
  // 8) routing
  gate_kernel<<<NTOKS / 4, 256, 0, stream>>>(xn, gw, topidx, topw, counts, loadAcc, zAcc);
  prefix_kernel<<<1, 64, 0, stream>>>(counts, offsets);
  scatter_kernel<<<NTOKS / 256, 256, 0, stream>>>(topidx, topw, offsets, cursors,
                                                  assign_token, assign_w, token_slot);
  // 9) routed experts, all 8 in one launch via gridDim.z
  mgemm<4, 2, true><<<dim3(64, 32, NEXP), 256, 0, stream>>>(
      xnb, ew1, ew2, nullptr, midr, 0, FFD, CDIM,
      assign_token, offsets, counts, (size_t)CDIM * FFD, nullptr, nullptr, nullptr, FFD);
  mgemm<3, 1, false><<<dim3(8, 32, NEXP), 256, 0, stream>>>(
      midr, ew3, nullptr, abuf, nullptr, 0, CDIM, FFD,
      nullptr, offsets, counts, (size_t)FFD * CDIM, nullptr, nullptr, assign_w, CDIM);
  // 10) combine + aux
  combine_kernel<<<NTOKS * CDIM / 4 / 256, 256, 0, stream>>>(hb, sho, abuf, token_slot,
                                                             aMoe, (float*)d_out);
  finalize_kernel<<<1, 64, 0, stream>>>(loadAcc, zAcc, (float*)d_out + (size_t)NTOKS * CDIM);
}